// Round 3
// baseline (129.503 us; speedup 1.0000x reference)
//
#include <hip/hip_runtime.h>
#include <math.h>

// Problem geometry
#define N_IMG   48          // B*C = 8*6
#define IMG_W   512
#define IMG_H   512
#define IMG_HW  (IMG_W*IMG_H)
#define OUT_W   506         // 512 - 6 (VALID 7x7)
#define OUT_H   506
#define BAND_H  23          // output rows per band; 23*22 = 506
#define N_BANDS 22
#define BAND_ROWS (BAND_H + 6)   // 29 input rows staged per band
#define HALF_COLS 253       // output columns per half-block
#define K1C     0.01f
#define K2C     0.03f

// ws layout:
//   double wsd[0]     = sum |diff|
//   double wsd[1]     = sum diff^2
//   double wsd[2..49] = per-image SSIM sum
//   unsigned wsu[0..47]  (at byte offset 400) = per-image min (ordered-uint map)
//   unsigned wsu[48..95]                      = per-image max (ordered-uint map)

__device__ __forceinline__ unsigned fmap(float f) {
  unsigned u = __float_as_uint(f);
  return (u & 0x80000000u) ? ~u : (u | 0x80000000u);
}
__device__ __forceinline__ float funmap(unsigned u) {
  return (u & 0x80000000u) ? __uint_as_float(u & 0x7FFFFFFFu)
                           : __uint_as_float(~u);
}

__global__ void init_ws(double* wsd, unsigned* wsu) {
  int t = threadIdx.x;
  if (t < 50) wsd[t] = 0.0;
  if (t < 48) { wsu[t] = 0xFFFFFFFFu; wsu[48 + t] = 0u; }
}

// Pass 1: per-image min/max of y_true*mask ONLY (reads 2 of 3 arrays).
// 64 chunks/image * 48 images = 3072 blocks of 256 threads, 4 float4/thread.
__global__ __launch_bounds__(256) void range_kernel(
    const float4* __restrict__ t4, const float4* __restrict__ m4,
    unsigned* __restrict__ wsu) {
  const int img = blockIdx.x >> 6;
  const int chunk = blockIdx.x & 63;
  const size_t base = (size_t)img * (IMG_HW / 4) + (size_t)chunk * (IMG_HW / 256);
  const int t = threadIdx.x;

  float mn = INFINITY, mx = -INFINITY;
#pragma unroll
  for (int k = 0; k < 4; ++k) {
    size_t idx = base + (size_t)k * 256 + t;
    float4 b = t4[idx], m = m4[idx];
    float v0 = b.x * m.x, v1 = b.y * m.y, v2 = b.z * m.z, v3 = b.w * m.w;
    mn = fminf(fminf(fminf(mn, v0), fminf(v1, v2)), v3);
    mx = fmaxf(fmaxf(fmaxf(mx, v0), fmaxf(v1, v2)), v3);
  }

#pragma unroll
  for (int off = 32; off; off >>= 1) {
    mn = fminf(mn, __shfl_down(mn, off));
    mx = fmaxf(mx, __shfl_down(mx, off));
  }
  __shared__ float rmn[4], rmx[4];
  int wave = t >> 6, lane = t & 63;
  if (lane == 0) { rmn[wave] = mn; rmx[wave] = mx; }
  __syncthreads();
  if (t == 0) {
    float MN = fminf(fminf(rmn[0], rmn[1]), fminf(rmn[2], rmn[3]));
    float MX = fmaxf(fmaxf(rmx[0], rmx[1]), fmaxf(rmx[2], rmx[3]));
    atomicMin(&wsu[img], fmap(MN));
    atomicMax(&wsu[48 + img], fmap(MX));
  }
}

// Pass 2: SSIM + fused MAE/MSE. One block per (image, band, column-half):
// 48*22*2 = 2112 blocks of 256 threads. Thread = output column within the
// half. Separable 7x7 box via LDS-staged rows (double-buffered) + a 6-deep
// register ring with STATIC slot indices (row loop unrolled by 6).
// Raw-sum SSIM algebra: the 1/49^2 and 1/(49*48) normalizations cancel in
// the ratio, so C1,C2 are pre-scaled by 2401 and 2352.
// MAE/MSE accumulated on the staging path with exact-once ownership:
//   rows: bands 0..20 own their first 23 staged rows; band 21 owns all 29.
//   cols: half 0 owns t<253 (not the extra 3); half 1 owns everything.

#define SSIM_ROW(J, ROW, WARM)                                               \
  {                                                                          \
    float nx0 = 0.f, ny0 = 0.f, nx1 = 0.f, ny1 = 0.f;                        \
    const bool pf = (ROW) < BAND_ROWS - 1;                                   \
    if (pf) {                                                                \
      size_t off = rowbase + (size_t)((ROW) + 1) * IMG_W + t;                \
      float m0 = mk[off];                                                    \
      nx0 = yp[off] * m0; ny0 = yt[off] * m0;                                \
      if (extra) {                                                           \
        size_t o2 = off + 256;                                               \
        float m1 = mk[o2];                                                   \
        nx1 = yp[o2] * m1; ny1 = yt[o2] * m1;                                \
      }                                                                      \
      if ((ROW) + 1 <= own_lim) {                                            \
        if (cown) {                                                          \
          float df = nx0 - ny0;                                              \
          bs1 += fabsf(df); bs2 = fmaf(df, df, bs2);                         \
        }                                                                    \
        if (eown) {                                                          \
          float df = nx1 - ny1;                                              \
          bs1 += fabsf(df); bs2 = fmaf(df, df, bs2);                         \
        }                                                                    \
      }                                                                      \
    }                                                                        \
    float hx = 0.f, hy = 0.f, hxx = 0.f, hyy = 0.f, hxy = 0.f;               \
    if (prod) {                                                              \
      _Pragma("unroll")                                                      \
      for (int jj = 0; jj < 7; ++jj) {                                       \
        float xv = lx[(J) & 1][t + jj], yv = ly[(J) & 1][t + jj];            \
        hx += xv; hy += yv;                                                  \
        hxx = fmaf(xv, xv, hxx);                                             \
        hyy = fmaf(yv, yv, hyy);                                             \
        hxy = fmaf(xv, yv, hxy);                                             \
      }                                                                      \
    }                                                                        \
    if (!(WARM)) {                                                           \
      float sx = vx_ + hx, sy = vy_ + hy;                                    \
      float sxx = vxx + hxx, syy = vyy + hyy, sxy = vxy + hxy;               \
      if (prod) {                                                            \
        float p = sx * sy;                                                   \
        float q = fmaf(sx, sx, sy * sy);                                     \
        float tt = sxx + syy;                                                \
        float A1 = fmaf(2.f, p, C1q);                                        \
        float A2 = fmaf(-2.f, p, fmaf(98.f, sxy, C2q));                      \
        float B1 = q + C1q;                                                  \
        float B2 = fmaf(49.f, tt, C2q - q);                                  \
        acc = fmaf(A1 * A2, __builtin_amdgcn_rcpf(B1 * B2), acc);            \
      }                                                                      \
      vx_ += hx - rx[(J)]; vy_ += hy - ry[(J)];                              \
      vxx += hxx - rxx[(J)]; vyy += hyy - ryy[(J)]; vxy += hxy - rxy[(J)];   \
    } else {                                                                 \
      vx_ += hx; vy_ += hy; vxx += hxx; vyy += hyy; vxy += hxy;              \
    }                                                                        \
    rx[(J)] = hx; ry[(J)] = hy;                                              \
    rxx[(J)] = hxx; ryy[(J)] = hyy; rxy[(J)] = hxy;                          \
    if (pf) {                                                                \
      lx[1 - ((J) & 1)][t] = nx0; ly[1 - ((J) & 1)][t] = ny0;                \
      if (extra) {                                                           \
        lx[1 - ((J) & 1)][t + 256] = nx1; ly[1 - ((J) & 1)][t + 256] = ny1;  \
      }                                                                      \
    }                                                                        \
    __syncthreads();                                                         \
  }

__global__ __launch_bounds__(256) void ssim_kernel(
    const float* __restrict__ yp, const float* __restrict__ yt,
    const float* __restrict__ mk, double* __restrict__ wsd,
    const unsigned* __restrict__ wsu) {
  const int bid = blockIdx.x;
  const int img = bid / (2 * N_BANDS);
  const int rem = bid % (2 * N_BANDS);
  const int band = rem >> 1;
  const int half = rem & 1;
  const int c0 = half * HALF_COLS;
  const int r0 = band * BAND_H;
  const size_t rowbase = (size_t)img * IMG_HW + (size_t)r0 * IMG_W + c0;
  const int t = threadIdx.x;
  const bool extra = (t < 3);          // staged cols 256..258 of this half
  const bool prod = (t < HALF_COLS);   // threads producing an output column
  // MAE/MSE ownership
  const int own_lim = (band == N_BANDS - 1) ? (BAND_ROWS - 1) : (BAND_H - 1);
  const bool cown = half || (t < HALF_COLS);
  const bool eown = extra && half;

  const float d = funmap(wsu[48 + img]) - funmap(wsu[img]);
  const float C1q = (K1C * d) * (K1C * d) * 2401.0f;   // C1 * 49^2
  const float C2q = (K2C * d) * (K2C * d) * 2352.0f;   // C2 * 49*48

  __shared__ float lx[2][264];
  __shared__ float ly[2][264];

  float rx[6] = {0,0,0,0,0,0}, ry[6] = {0,0,0,0,0,0};
  float rxx[6] = {0,0,0,0,0,0}, ryy[6] = {0,0,0,0,0,0}, rxy[6] = {0,0,0,0,0,0};
  float vx_ = 0.f, vy_ = 0.f, vxx = 0.f, vyy = 0.f, vxy = 0.f;
  float acc = 0.f, bs1 = 0.f, bs2 = 0.f;

  // stage input row 0 into buffer 0 (row 0 always owned: 0 <= own_lim)
  {
    size_t off = rowbase + t;
    float m0 = mk[off];
    float x0 = yp[off] * m0, y0 = yt[off] * m0;
    lx[0][t] = x0; ly[0][t] = y0;
    if (cown) {
      float df = x0 - y0;
      bs1 += fabsf(df); bs2 = fmaf(df, df, bs2);
    }
    if (extra) {
      size_t o2 = off + 256;
      float m1 = mk[o2];
      float x1 = yp[o2] * m1, y1 = yt[o2] * m1;
      lx[0][t + 256] = x1; ly[0][t + 256] = y1;
      if (eown) {
        float df = x1 - y1;
        bs1 += fabsf(df); bs2 = fmaf(df, df, bs2);
      }
    }
  }
  __syncthreads();

  // warm-up rows 0..5 (ring slots 0..5, no output)
  SSIM_ROW(0, 0, true)
  SSIM_ROW(1, 1, true)
  SSIM_ROW(2, 2, true)
  SSIM_ROW(3, 3, true)
  SSIM_ROW(4, 4, true)
  SSIM_ROW(5, 5, true)

  // output rows: input rows 6..23 in three unrolled groups of 6
  for (int g = 0; g < 3; ++g) {
    const int rbase = 6 + 6 * g;
    SSIM_ROW(0, rbase + 0, false)
    SSIM_ROW(1, rbase + 1, false)
    SSIM_ROW(2, rbase + 2, false)
    SSIM_ROW(3, rbase + 3, false)
    SSIM_ROW(4, rbase + 4, false)
    SSIM_ROW(5, rbase + 5, false)
  }
  // tail rows 24..28 (slots 0..4)
  SSIM_ROW(0, 24, false)
  SSIM_ROW(1, 25, false)
  SSIM_ROW(2, 26, false)
  SSIM_ROW(3, 27, false)
  SSIM_ROW(4, 28, false)

  // block reduction -> accumulators
#pragma unroll
  for (int off = 32; off; off >>= 1) {
    acc += __shfl_down(acc, off);
    bs1 += __shfl_down(bs1, off);
    bs2 += __shfl_down(bs2, off);
  }
  __shared__ float warr[4], w1[4], w2[4];
  int wave = t >> 6, lane = t & 63;
  if (lane == 0) { warr[wave] = acc; w1[wave] = bs1; w2[wave] = bs2; }
  __syncthreads();
  if (t == 0) {
    float s = warr[0] + warr[1] + warr[2] + warr[3];
    float a1 = w1[0] + w1[1] + w1[2] + w1[3];
    float a2 = w2[0] + w2[1] + w2[2] + w2[3];
    atomicAdd(&wsd[2 + img], (double)s);
    atomicAdd(&wsd[0], (double)a1);
    atomicAdd(&wsd[1], (double)a2);
  }
}

__global__ void finalize_kernel(const double* __restrict__ wsd,
                                float* __restrict__ out) {
  if (threadIdx.x == 0 && blockIdx.x == 0) {
    const double N = (double)N_IMG * (double)IMG_HW;   // 12582912
    double mae = wsd[0] / N;
    double mse = wsd[1] / N;
    double ssum = 0.0;
    for (int i = 0; i < N_IMG; ++i) ssum += wsd[2 + i];
    double smean = ssum / ((double)OUT_W * (double)OUT_H * (double)N_IMG);
    double ssim_loss = 1.0 - smean;
    double total = 1.0 * mae + 0.5 * mse + 0.2 * ssim_loss;
    out[0] = (float)total;
    out[1] = (float)mae;
    out[2] = (float)mse;
    out[3] = (float)ssim_loss;
  }
}

extern "C" void kernel_launch(void* const* d_in, const int* in_sizes, int n_in,
                              void* d_out, int out_size, void* d_ws,
                              size_t ws_size, hipStream_t stream) {
  const float* yp = (const float*)d_in[0];
  const float* yt = (const float*)d_in[1];
  const float* mk = (const float*)d_in[2];
  float* out = (float*)d_out;
  double* wsd = (double*)d_ws;
  unsigned* wsu = (unsigned*)((char*)d_ws + 400);

  hipLaunchKernelGGL(init_ws, dim3(1), dim3(64), 0, stream, wsd, wsu);
  hipLaunchKernelGGL(range_kernel, dim3(N_IMG * 64), dim3(256), 0, stream,
                     (const float4*)yt, (const float4*)mk, wsu);
  hipLaunchKernelGGL(ssim_kernel, dim3(N_IMG * N_BANDS * 2), dim3(256), 0,
                     stream, yp, yt, mk, wsd, wsu);
  hipLaunchKernelGGL(finalize_kernel, dim3(1), dim3(64), 0, stream, wsd, out);
}

// Round 4
// 95.920 us; speedup vs baseline: 1.3501x; 1.3501x over previous
//
#include <hip/hip_runtime.h>
#include <math.h>

// Problem geometry
#define N_IMG   48          // B*C = 8*6
#define IMG_W   512
#define IMG_H   512
#define IMG_HW  (IMG_W*IMG_H)
#define OUT_W   506         // 512 - 6 (VALID 7x7)
#define OUT_H   506
#define BAND_H  46          // output rows per band; 46*11 = 506
#define N_BANDS 11
#define HALF_COLS 253       // output columns per half-block
#define K1C     0.01f
#define K2C     0.03f

// ws layout (doubles first, then uints):
//   wsd[0..63]    = sum |diff| partial slots
//   wsd[64..127]  = sum diff^2 partial slots
//   wsd[128..175] = per-image SSIM sum
//   wsu (byte offset 1408): [0..47] per-image min (ordered-uint map),
//                           [48..95] per-image max
#define SLOT_S1   0
#define SLOT_S2   64
#define SLOT_SSIM 128
#define N_DBL     176
#define WSU_OFF   1408

__device__ __forceinline__ unsigned fmap(float f) {
  unsigned u = __float_as_uint(f);
  return (u & 0x80000000u) ? ~u : (u | 0x80000000u);
}
__device__ __forceinline__ float funmap(unsigned u) {
  return (u & 0x80000000u) ? __uint_as_float(u & 0x7FFFFFFFu)
                           : __uint_as_float(~u);
}

__global__ void init_ws(double* wsd, unsigned* wsu) {
  int t = threadIdx.x;
  if (t < N_DBL) wsd[t] = 0.0;
  if (t < 48) { wsu[t] = 0xFFFFFFFFu; wsu[48 + t] = 0u; }
}

// Pass 1 (fused stats): per-image min/max of y_true*mask + global MAE/MSE
// sums. 64 chunks/image * 48 images = 3072 blocks, 256 threads, 4 float4
// per thread per array. MAE/MSE partials go to 64 slotted addresses
// (chain depth 48) -- NO hot-address f64 atomic chain.
__global__ __launch_bounds__(256) void stat_kernel(
    const float4* __restrict__ p4, const float4* __restrict__ t4,
    const float4* __restrict__ m4, double* __restrict__ wsd,
    unsigned* __restrict__ wsu) {
  const int img = blockIdx.x >> 6;
  const int chunk = blockIdx.x & 63;
  const size_t base = (size_t)img * (IMG_HW / 4) + (size_t)chunk * (IMG_HW / 256);
  const int t = threadIdx.x;

  float s1 = 0.f, s2 = 0.f, mn = INFINITY, mx = -INFINITY;
#pragma unroll
  for (int k = 0; k < 4; ++k) {
    size_t idx = base + (size_t)k * 256 + t;
    float4 a = p4[idx], b = t4[idx], m = m4[idx];
    {
      float d = (a.x - b.x) * m.x, v = b.x * m.x;
      s1 += fabsf(d); s2 = fmaf(d, d, s2);
      mn = fminf(mn, v); mx = fmaxf(mx, v);
    }
    {
      float d = (a.y - b.y) * m.y, v = b.y * m.y;
      s1 += fabsf(d); s2 = fmaf(d, d, s2);
      mn = fminf(mn, v); mx = fmaxf(mx, v);
    }
    {
      float d = (a.z - b.z) * m.z, v = b.z * m.z;
      s1 += fabsf(d); s2 = fmaf(d, d, s2);
      mn = fminf(mn, v); mx = fmaxf(mx, v);
    }
    {
      float d = (a.w - b.w) * m.w, v = b.w * m.w;
      s1 += fabsf(d); s2 = fmaf(d, d, s2);
      mn = fminf(mn, v); mx = fmaxf(mx, v);
    }
  }

#pragma unroll
  for (int off = 32; off; off >>= 1) {
    s1 += __shfl_down(s1, off);
    s2 += __shfl_down(s2, off);
    mn = fminf(mn, __shfl_down(mn, off));
    mx = fmaxf(mx, __shfl_down(mx, off));
  }
  __shared__ float r1[4], r2[4], rmn[4], rmx[4];
  int wave = t >> 6, lane = t & 63;
  if (lane == 0) { r1[wave] = s1; r2[wave] = s2; rmn[wave] = mn; rmx[wave] = mx; }
  __syncthreads();
  if (t == 0) {
    float S1 = r1[0] + r1[1] + r1[2] + r1[3];
    float S2 = r2[0] + r2[1] + r2[2] + r2[3];
    float MN = fminf(fminf(rmn[0], rmn[1]), fminf(rmn[2], rmn[3]));
    float MX = fmaxf(fmaxf(rmx[0], rmx[1]), fmaxf(rmx[2], rmx[3]));
    int slot = blockIdx.x & 63;
    atomicAdd(&wsd[SLOT_S1 + slot], (double)S1);
    atomicAdd(&wsd[SLOT_S2 + slot], (double)S2);
    atomicMin(&wsu[img], fmap(MN));
    atomicMax(&wsu[48 + img], fmap(MX));
  }
}

// Pass 2: SSIM only (proven R1 structure). One block per (image, band,
// column-half): 48*11*2 = 1056 blocks of 256 threads. Thread = output
// column within the half. Separable 7x7 box via LDS-staged rows
// (double-buffered, prefetch consumed ONLY at the LDS-write point) + a
// 6-deep register ring with STATIC slot indices (row loop unrolled by 6).
// Raw-sum algebra: 1/49^2 and 1/(49*48) cancel in the ratio; C1,C2
// pre-scaled by 2401 and 2352.

#define SSIM_ROW(J, ROW, WARM, LAST)                                        \
  {                                                                          \
    float nx0 = 0.f, ny0 = 0.f, nx1 = 0.f, ny1 = 0.f;                        \
    const bool pf = !(LAST);                                                 \
    if (pf) {                                                                \
      size_t off = rowbase + (size_t)((ROW) + 1) * IMG_W + t;                \
      float m0 = mk[off];                                                    \
      nx0 = yp[off] * m0; ny0 = yt[off] * m0;                                \
      if (extra) {                                                           \
        size_t o2 = off + 256;                                               \
        float m1 = mk[o2];                                                   \
        nx1 = yp[o2] * m1; ny1 = yt[o2] * m1;                                \
      }                                                                      \
    }                                                                        \
    float hx = 0.f, hy = 0.f, hxx = 0.f, hyy = 0.f, hxy = 0.f;               \
    if (prod) {                                                              \
      _Pragma("unroll")                                                      \
      for (int jj = 0; jj < 7; ++jj) {                                       \
        float xv = lx[(J) & 1][t + jj], yv = ly[(J) & 1][t + jj];            \
        hx += xv; hy += yv;                                                  \
        hxx = fmaf(xv, xv, hxx);                                             \
        hyy = fmaf(yv, yv, hyy);                                             \
        hxy = fmaf(xv, yv, hxy);                                             \
      }                                                                      \
    }                                                                        \
    if (!(WARM)) {                                                           \
      float sx = vx_ + hx, sy = vy_ + hy;                                    \
      float sxx = vxx + hxx, syy = vyy + hyy, sxy = vxy + hxy;               \
      if (prod) {                                                            \
        float p = sx * sy;                                                   \
        float q = fmaf(sx, sx, sy * sy);                                     \
        float tt = sxx + syy;                                                \
        float A1 = fmaf(2.f, p, C1q);                                        \
        float A2 = fmaf(-2.f, p, fmaf(98.f, sxy, C2q));                      \
        float B1 = q + C1q;                                                  \
        float B2 = fmaf(49.f, tt, C2q - q);                                  \
        acc = fmaf(A1 * A2, __builtin_amdgcn_rcpf(B1 * B2), acc);            \
      }                                                                      \
      vx_ += hx - rx[(J)]; vy_ += hy - ry[(J)];                              \
      vxx += hxx - rxx[(J)]; vyy += hyy - ryy[(J)]; vxy += hxy - rxy[(J)];   \
    } else {                                                                 \
      vx_ += hx; vy_ += hy; vxx += hxx; vyy += hyy; vxy += hxy;              \
    }                                                                        \
    rx[(J)] = hx; ry[(J)] = hy;                                              \
    rxx[(J)] = hxx; ryy[(J)] = hyy; rxy[(J)] = hxy;                          \
    if (pf) {                                                                \
      lx[1 - ((J) & 1)][t] = nx0; ly[1 - ((J) & 1)][t] = ny0;                \
      if (extra) {                                                           \
        lx[1 - ((J) & 1)][t + 256] = nx1; ly[1 - ((J) & 1)][t + 256] = ny1;  \
      }                                                                      \
    }                                                                        \
    __syncthreads();                                                         \
  }

__global__ __launch_bounds__(256) void ssim_kernel(
    const float* __restrict__ yp, const float* __restrict__ yt,
    const float* __restrict__ mk, double* __restrict__ wsd,
    const unsigned* __restrict__ wsu) {
  const int bid = blockIdx.x;
  const int img = bid / (2 * N_BANDS);
  const int rem = bid % (2 * N_BANDS);
  const int band = rem >> 1;
  const int half = rem & 1;
  const int c0 = half * HALF_COLS;
  const int r0 = band * BAND_H;
  const size_t rowbase = (size_t)img * IMG_HW + (size_t)r0 * IMG_W + c0;
  const int t = threadIdx.x;
  const bool extra = (t < 3);          // staged cols 256..258 of this half
  const bool prod = (t < HALF_COLS);   // threads producing an output column

  const float d = funmap(wsu[48 + img]) - funmap(wsu[img]);
  const float C1q = (K1C * d) * (K1C * d) * 2401.0f;   // C1 * 49^2
  const float C2q = (K2C * d) * (K2C * d) * 2352.0f;   // C2 * 49*48

  __shared__ float lx[2][264];
  __shared__ float ly[2][264];

  float rx[6] = {0,0,0,0,0,0}, ry[6] = {0,0,0,0,0,0};
  float rxx[6] = {0,0,0,0,0,0}, ryy[6] = {0,0,0,0,0,0}, rxy[6] = {0,0,0,0,0,0};
  float vx_ = 0.f, vy_ = 0.f, vxx = 0.f, vyy = 0.f, vxy = 0.f;
  float acc = 0.f;

  // stage input row 0 into buffer 0
  {
    size_t off = rowbase + t;
    float m0 = mk[off];
    lx[0][t] = yp[off] * m0; ly[0][t] = yt[off] * m0;
    if (extra) {
      size_t o2 = off + 256;
      float m1 = mk[o2];
      lx[0][t + 256] = yp[o2] * m1; ly[0][t + 256] = yt[o2] * m1;
    }
  }
  __syncthreads();

  // warm-up rows 0..5 (ring slots 0..5, no output)
  SSIM_ROW(0, 0, true, false)
  SSIM_ROW(1, 1, true, false)
  SSIM_ROW(2, 2, true, false)
  SSIM_ROW(3, 3, true, false)
  SSIM_ROW(4, 4, true, false)
  SSIM_ROW(5, 5, true, false)

  // output rows: input rows 6..51, slot = row mod 6 (static per position)
  for (int g = 0; g < 8; ++g) {
    const int rbase = 6 + 6 * g;
    SSIM_ROW(0, rbase + 0, false, false)
    SSIM_ROW(1, rbase + 1, false, false)
    SSIM_ROW(2, rbase + 2, false, false)
    SSIM_ROW(3, rbase + 3, false, (rbase + 3) == 51)
    if (rbase + 4 < 52) SSIM_ROW(4, rbase + 4, false, false)
    if (rbase + 5 < 52) SSIM_ROW(5, rbase + 5, false, false)
  }

  // block reduction -> per-image accumulator (chain depth 22/address: fine)
#pragma unroll
  for (int off = 32; off; off >>= 1) acc += __shfl_down(acc, off);
  __shared__ float warr[4];
  int wave = t >> 6, lane = t & 63;
  if (lane == 0) warr[wave] = acc;
  __syncthreads();
  if (t == 0) {
    float s = warr[0] + warr[1] + warr[2] + warr[3];
    atomicAdd(&wsd[SLOT_SSIM + img], (double)s);
  }
}

__global__ void finalize_kernel(const double* __restrict__ wsd,
                                float* __restrict__ out) {
  if (threadIdx.x == 0 && blockIdx.x == 0) {
    const double N = (double)N_IMG * (double)IMG_HW;   // 12582912
    double mae = 0.0, mse = 0.0, ssum = 0.0;
    for (int i = 0; i < 64; ++i) { mae += wsd[SLOT_S1 + i]; mse += wsd[SLOT_S2 + i]; }
    mae /= N; mse /= N;
    for (int i = 0; i < N_IMG; ++i) ssum += wsd[SLOT_SSIM + i];
    double smean = ssum / ((double)OUT_W * (double)OUT_H * (double)N_IMG);
    double ssim_loss = 1.0 - smean;
    double total = 1.0 * mae + 0.5 * mse + 0.2 * ssim_loss;
    out[0] = (float)total;
    out[1] = (float)mae;
    out[2] = (float)mse;
    out[3] = (float)ssim_loss;
  }
}

extern "C" void kernel_launch(void* const* d_in, const int* in_sizes, int n_in,
                              void* d_out, int out_size, void* d_ws,
                              size_t ws_size, hipStream_t stream) {
  const float* yp = (const float*)d_in[0];
  const float* yt = (const float*)d_in[1];
  const float* mk = (const float*)d_in[2];
  float* out = (float*)d_out;
  double* wsd = (double*)d_ws;
  unsigned* wsu = (unsigned*)((char*)d_ws + WSU_OFF);

  hipLaunchKernelGGL(init_ws, dim3(1), dim3(256), 0, stream, wsd, wsu);
  hipLaunchKernelGGL(stat_kernel, dim3(N_IMG * 64), dim3(256), 0, stream,
                     (const float4*)yp, (const float4*)yt, (const float4*)mk,
                     wsd, wsu);
  hipLaunchKernelGGL(ssim_kernel, dim3(N_IMG * N_BANDS * 2), dim3(256), 0,
                     stream, yp, yt, mk, wsd, wsu);
  hipLaunchKernelGGL(finalize_kernel, dim3(1), dim3(64), 0, stream, wsd, out);
}